// Round 4
// baseline (427.597 us; speedup 1.0000x reference)
//
#include <hip/hip_runtime.h>
#include <hip/hip_bf16.h>
#include <math.h>

typedef __bf16 bf16_t;
typedef __bf16 bf16x8 __attribute__((ext_vector_type(8)));
typedef __bf16 bf16x4 __attribute__((ext_vector_type(4)));
typedef float f32x4 __attribute__((ext_vector_type(4)));

#define DEVI __device__ __forceinline__

DEVI f32x4 mfma16(bf16x8 a, bf16x8 b, f32x4 c) {
  return __builtin_amdgcn_mfma_f32_16x16x32_bf16(a, b, c, 0, 0, 0);
}
DEVI bf16x8 ld8(const bf16_t* p) { return *reinterpret_cast<const bf16x8*>(p); }

// Fragment layout: element (row, k) of an MFMA A/B operand matrix lives at
//   ((row>>4)*(K/32) + (k>>5))*512 + ((k>>3)&3)*128 + (row&15)*8 + (k&7)
// so consumer lane l of (rowtile, kchunk) reads 8 contiguous bf16 at
//   ((rowtile*(K/32)+kchunk)<<9) + l*8.

// ---------------------------------------------------------------------------
// K0: tiled transpose + bf16 convert + FRAGMENT swizzle of all weights.
// ---------------------------------------------------------------------------
struct WtArgs { const float* s0; const float* s1; const float* s2; const float* s3;
                const float* s4; const float* s5; const float* s6; const float* s7;
                const float* s8; const float* s9; const float* s10; const float* s11; };

__global__ __launch_bounds__(256) void k_wtrans(WtArgs A, bf16_t* __restrict__ wt) {
  constexpr int offs[12] = {0,65536,131072,196608,262144,458752,655360,851968,
                            1048576,1081344,1114112,1179648};
  constexpr int Ks[12]   = {256,256,256,256,256,256,256,256,256,128,256,256};
  constexpr int Ns[12]   = {256,256,256,256,768,768,768,768,128,256,256,256};
  const int m = blockIdx.y;
  const int K = Ks[m], N = Ns[m];
  const int tn = N >> 6;
  const int tile = blockIdx.x;
  if (tile >= (K >> 6) * tn) return;
  const int tk = tile / tn, tc = tile - tk * tn;
  const float* sp;
  switch (m) {
    case 0: sp = A.s0; break; case 1: sp = A.s1; break; case 2: sp = A.s2; break;
    case 3: sp = A.s3; break; case 4: sp = A.s4; break; case 5: sp = A.s5; break;
    case 6: sp = A.s6; break; case 7: sp = A.s7; break; case 8: sp = A.s8; break;
    case 9: sp = A.s9; break; case 10: sp = A.s10; break; default: sp = A.s11; break;
  }
  __shared__ float ts[64][65];
  const int t = threadIdx.x;
  const int k0 = tk * 64, n0 = tc * 64;
  {
    const int c = t & 63, rq = t >> 6;
    #pragma unroll
    for (int i = 0; i < 16; ++i) {
      const int r = rq * 16 + i;
      ts[r][c] = sp[(size_t)(k0 + r) * N + n0 + c];
    }
  }
  __syncthreads();
  bf16_t* dst = wt + offs[m];
  const int n_l = t & 63, kq = t >> 6;
  #pragma unroll
  for (int h = 0; h < 2; ++h) {
    const int k_l = kq * 16 + h * 8;
    bf16x8 pk;
    #pragma unroll
    for (int e = 0; e < 8; ++e) pk[e] = (bf16_t)ts[k_l + e][n_l];
    const int n_g = n0 + n_l, k_g = k0 + k_l;
    const int nt = n_g >> 4, kc = k_g >> 5;
    const int lane = (((k_g >> 3) & 3) << 4) + (n_g & 15);
    *reinterpret_cast<bf16x8*>(dst + (((size_t)(nt * (K >> 5) + kc)) << 9) + lane * 8) = pk;
  }
}

// ---------------------------------------------------------------------------
// K_init: slots f32 -> h_f32 (row-major) / h_bf (fragment layout)
// ---------------------------------------------------------------------------
__global__ __launch_bounds__(256) void k_init(const float* __restrict__ in_slots,
                                              const float* __restrict__ tgt_slots,
                                              float* __restrict__ h_f32,
                                              bf16_t* __restrict__ h_bf) {
  int idx = blockIdx.x * 256 + threadIdx.x;
  int side = idx >> 14, j = idx & 16383;
  int s = j >> 8, d = j & 255;
  float x = (side ? tgt_slots : in_slots)[j];
  h_f32[idx] = x;
  h_bf[side*16384 + (((s>>4)*8 + (d>>5))<<9) + ((d>>3)&3)*128 + (s&15)*8 + (d&7)] = (bf16_t)x;
}

// ---------------------------------------------------------------------------
// K_ln (split path): streaming LN of inputs+target -> anormF (fragment layout)
// One row per wave-iteration; 16 rows per wave; low regs -> high occupancy.
// ---------------------------------------------------------------------------
__global__ __launch_bounds__(256) void k_ln(
    const float* __restrict__ inputs, const float* __restrict__ target,
    const float* __restrict__ g_in, const float* __restrict__ b_in,
    const float* __restrict__ g_tgt, const float* __restrict__ b_tgt,
    bf16_t* __restrict__ anormF) {
  const int wg = blockIdx.x * 4 + (threadIdx.x >> 6);   // global wave id, 0..8191
  const int l = threadIdx.x & 63;
  const int r0 = wg * 16;                                // 16 rows per wave
  const int side = r0 >> 16;
  const int m0 = r0 & 65535;
  const float* src = side ? target : inputs;
  const float4 g4 = *reinterpret_cast<const float4*>((side ? g_tgt : g_in) + l*4);
  const float4 b4 = *reinterpret_cast<const float4*>((side ? b_tgt : b_in) + l*4);
  bf16_t* dst = anormF + (size_t)side * 16777216;
  const int d = l * 4;
  const size_t doff = (size_t)((d>>5) << 9) + ((d>>3)&3)*128 + (d&7);
  #pragma unroll
  for (int ii = 0; ii < 4; ++ii) {
    float4 x[4];
    #pragma unroll
    for (int j = 0; j < 4; ++j)
      x[j] = *reinterpret_cast<const float4*>(src + (size_t)(m0 + ii*4 + j)*256 + d);
    #pragma unroll
    for (int j = 0; j < 4; ++j) {
      const int m = m0 + ii*4 + j;
      float s1 = x[j].x + x[j].y + x[j].z + x[j].w;
      float s2 = x[j].x*x[j].x + x[j].y*x[j].y + x[j].z*x[j].z + x[j].w*x[j].w;
      #pragma unroll
      for (int msk = 1; msk < 64; msk <<= 1) { s1 += __shfl_xor(s1, msk); s2 += __shfl_xor(s2, msk); }
      const float mean = s1 * (1.f/256.f);
      const float rstd = rsqrtf(s2 * (1.f/256.f) - mean*mean + 1e-5f);
      bf16x4 pk;
      pk[0] = (bf16_t)((x[j].x - mean) * rstd * g4.x + b4.x);
      pk[1] = (bf16_t)((x[j].y - mean) * rstd * g4.y + b4.y);
      pk[2] = (bf16_t)((x[j].z - mean) * rstd * g4.z + b4.z);
      pk[3] = (bf16_t)((x[j].w - mean) * rstd * g4.w + b4.w);
      *reinterpret_cast<bf16x4*>(dst + (size_t)(((m>>4)*8) << 9) + (m&15)*8 + doff) = pk;
    }
  }
}

// ---------------------------------------------------------------------------
// K_proj (split path): pure-GEMM projections, no LDS, no syncthreads.
//   side0: in_k = anorm @ Wk (frag out) ; in_v^T = Wv(A) @ anorm^T(B)
//   side1: tgt_v^T = Wvt(A) @ anorm^T(B)
// ---------------------------------------------------------------------------
__global__ __launch_bounds__(256) void k_proj(
    const bf16_t* __restrict__ anormF,
    const bf16_t* __restrict__ wkF, const bf16_t* __restrict__ wvF, const bf16_t* __restrict__ wvtF,
    const float* __restrict__ bk, const float* __restrict__ bv, const float* __restrict__ bvt,
    bf16_t* __restrict__ in_kF, bf16_t* __restrict__ in_vF, bf16_t* __restrict__ tgt_vF) {
  const int side = blockIdx.y;
  const int t = threadIdx.x, l = t & 63, w = t >> 6, l16 = l & 15, l4 = l >> 4;
  const int e = l16 & 7, lh = l16 >> 3;
  const bf16_t* aF = anormF + (size_t)side * 16777216;

  if (side == 0) {  // C1 = anorm @ Wk -> in_kF
    f32x4 acc[4][4] = {};
    for (int ks = 0; ks < 8; ++ks) {
      bf16x8 a[4], b[4];
      #pragma unroll
      for (int mi = 0; mi < 4; ++mi)
        a[mi] = ld8(aF + (((size_t)((blockIdx.x*4 + mi)*8 + ks)) << 9) + l*8);
      #pragma unroll
      for (int ni = 0; ni < 4; ++ni)
        b[ni] = ld8(wkF + (((size_t)((w*4 + ni)*8 + ks)) << 9) + l*8);
      #pragma unroll
      for (int mi = 0; mi < 4; ++mi)
        #pragma unroll
        for (int ni = 0; ni < 4; ++ni) acc[mi][ni] = mfma16(a[mi], b[ni], acc[mi][ni]);
    }
    #pragma unroll
    for (int mi = 0; mi < 4; ++mi)
      #pragma unroll
      for (int ni = 0; ni < 4; ++ni) {
        const int d = w*64 + ni*16 + l16;
        const float bias = bk[d];
        const int kc = w*2 + (ni >> 1);
        const int l4p = (ni & 1)*2 + lh;
        bf16_t* outp = in_kF + ((((size_t)(blockIdx.x*4 + mi))*8 + kc) << 9) + l4p*128 + e;
        #pragma unroll
        for (int rr = 0; rr < 4; ++rr)
          outp[(l4*4 + rr)*8] = (bf16_t)(acc[mi][ni][rr] + bias);
      }
  }
  {  // C2 = W(as A) @ anorm^T(as B) -> vF
    const bf16_t* WF = side ? wvtF : wvF;
    const float* bias = side ? bvt : bv;
    bf16_t* out = side ? tgt_vF : in_vF;
    f32x4 acc[4][4] = {};
    for (int ks = 0; ks < 8; ++ks) {
      bf16x8 a[4], b[4];
      #pragma unroll
      for (int mi = 0; mi < 4; ++mi)
        a[mi] = ld8(WF + (((size_t)((w*4 + mi)*8 + ks)) << 9) + l*8);
      #pragma unroll
      for (int ni = 0; ni < 4; ++ni)
        b[ni] = ld8(aF + (((size_t)((blockIdx.x*4 + ni)*8 + ks)) << 9) + l*8);
      #pragma unroll
      for (int mi = 0; mi < 4; ++mi)
        #pragma unroll
        for (int ni = 0; ni < 4; ++ni) acc[mi][ni] = mfma16(a[mi], b[ni], acc[mi][ni]);
    }
    #pragma unroll
    for (int mi = 0; mi < 4; ++mi)
      #pragma unroll
      for (int ni = 0; ni < 4; ++ni) {
        const int dt = w*4 + mi;
        const int mc = blockIdx.x*2 + (ni >> 1);
        const int l4p = (ni & 1)*2 + lh;
        bf16_t* outp = out + ((((size_t)dt)*2048 + mc) << 9) + l4p*128 + e;
        #pragma unroll
        for (int rr = 0; rr < 4; ++rr) {
          const int d = w*64 + mi*16 + l4*4 + rr;
          outp[(l4*4 + rr)*8] = (bf16_t)(acc[mi][ni][rr] + bias[d]);
        }
      }
  }
}

// ---------------------------------------------------------------------------
// Fallback fused Phase A (used when workspace too small for anormF).
// ---------------------------------------------------------------------------
__global__ __launch_bounds__(256) void k_phaseA(
    const float* __restrict__ inputs, const float* __restrict__ target,
    const float* __restrict__ ln_in_g, const float* __restrict__ ln_in_b,
    const float* __restrict__ ln_tgt_g, const float* __restrict__ ln_tgt_b,
    const bf16_t* __restrict__ wkF, const bf16_t* __restrict__ wvF, const bf16_t* __restrict__ wvtF,
    const float* __restrict__ bk, const float* __restrict__ bv, const float* __restrict__ bvt,
    bf16_t* __restrict__ in_kF, bf16_t* __restrict__ in_vF, bf16_t* __restrict__ tgt_vF) {
  const int side = blockIdx.y;
  const int m0 = blockIdx.x * 64;
  const int t = threadIdx.x, l = t & 63, w = t >> 6;
  __shared__ __align__(16) bf16_t anorm[64][264];
  const float* src = side ? target : inputs;
  const float* gp = side ? ln_tgt_g : ln_in_g;
  const float* bp = side ? ln_tgt_b : ln_in_b;
  const float4 g4 = *reinterpret_cast<const float4*>(gp + l * 4);
  const float4 b4 = *reinterpret_cast<const float4*>(bp + l * 4);
  float4 v[16];
  #pragma unroll
  for (int i = 0; i < 16; ++i)
    v[i] = *reinterpret_cast<const float4*>(src + (size_t)(m0 + w*16 + i) * 256 + l * 4);
  #pragma unroll
  for (int i = 0; i < 16; ++i) {
    float s1 = v[i].x + v[i].y + v[i].z + v[i].w;
    float s2 = v[i].x*v[i].x + v[i].y*v[i].y + v[i].z*v[i].z + v[i].w*v[i].w;
    #pragma unroll
    for (int msk = 1; msk < 64; msk <<= 1) { s1 += __shfl_xor(s1, msk); s2 += __shfl_xor(s2, msk); }
    const float mean = s1 * (1.f/256.f);
    const float rstd = rsqrtf(s2 * (1.f/256.f) - mean*mean + 1e-5f);
    bf16x4 pk;
    pk[0] = (bf16_t)((v[i].x - mean) * rstd * g4.x + b4.x);
    pk[1] = (bf16_t)((v[i].y - mean) * rstd * g4.y + b4.y);
    pk[2] = (bf16_t)((v[i].z - mean) * rstd * g4.z + b4.z);
    pk[3] = (bf16_t)((v[i].w - mean) * rstd * g4.w + b4.w);
    *reinterpret_cast<bf16x4*>(&anorm[w*16 + i][l*4]) = pk;
  }
  __syncthreads();
  const int l16 = l & 15, l4 = l >> 4;
  const int e = l16 & 7, lh = l16 >> 3;

  if (side == 0) {
    f32x4 acc[4][4] = {};
    for (int ks = 0; ks < 8; ++ks) {
      const int k = ks*32 + l4*8;
      bf16x8 a[4], b[4];
      #pragma unroll
      for (int mi = 0; mi < 4; ++mi) a[mi] = ld8(&anorm[mi*16 + l16][k]);
      #pragma unroll
      for (int ni = 0; ni < 4; ++ni) b[ni] = ld8(wkF + (((size_t)((w*4 + ni)*8 + ks)) << 9) + l*8);
      #pragma unroll
      for (int mi = 0; mi < 4; ++mi)
        #pragma unroll
        for (int ni = 0; ni < 4; ++ni) acc[mi][ni] = mfma16(a[mi], b[ni], acc[mi][ni]);
    }
    #pragma unroll
    for (int mi = 0; mi < 4; ++mi)
      #pragma unroll
      for (int ni = 0; ni < 4; ++ni) {
        const int d = w*64 + ni*16 + l16;
        const float bias = bk[d];
        const int kc = w*2 + (ni >> 1);
        const int l4p = (ni & 1)*2 + lh;
        bf16_t* outp = in_kF + ((((size_t)(blockIdx.x*4 + mi))*8 + kc) << 9) + l4p*128 + e;
        #pragma unroll
        for (int rr = 0; rr < 4; ++rr)
          outp[(l4*4 + rr)*8] = (bf16_t)(acc[mi][ni][rr] + bias);
      }
  }
  {
    const bf16_t* WF = side ? wvtF : wvF;
    const float* bias = side ? bvt : bv;
    bf16_t* out = side ? tgt_vF : in_vF;
    f32x4 acc[4][4] = {};
    for (int ks = 0; ks < 8; ++ks) {
      const int k = ks*32 + l4*8;
      bf16x8 a[4], b[4];
      #pragma unroll
      for (int mi = 0; mi < 4; ++mi) a[mi] = ld8(WF + (((size_t)((w*4 + mi)*8 + ks)) << 9) + l*8);
      #pragma unroll
      for (int ni = 0; ni < 4; ++ni) b[ni] = ld8(&anorm[ni*16 + l16][k]);
      #pragma unroll
      for (int mi = 0; mi < 4; ++mi)
        #pragma unroll
        for (int ni = 0; ni < 4; ++ni) acc[mi][ni] = mfma16(a[mi], b[ni], acc[mi][ni]);
    }
    #pragma unroll
    for (int mi = 0; mi < 4; ++mi)
      #pragma unroll
      for (int ni = 0; ni < 4; ++ni) {
        const int dt = w*4 + mi;
        const int mc = blockIdx.x*2 + (ni >> 1);
        const int l4p = (ni & 1)*2 + lh;
        bf16_t* outp = out + ((((size_t)dt)*2048 + mc) << 9) + l4p*128 + e;
        #pragma unroll
        for (int rr = 0; rr < 4; ++rr) {
          const int d = w*64 + mi*16 + l4*4 + rr;
          outp[(l4*4 + rr)*8] = (bf16_t)(acc[mi][ni][rr] + bias[d]);
        }
      }
  }
}

// ---------------------------------------------------------------------------
// K_q: q (fragment layout) = bf16( (LN(in_slots) @ Wq + bq) / 16 ) — 1 block
// ---------------------------------------------------------------------------
__global__ __launch_bounds__(256) void k_q(
    const float* __restrict__ h_in,
    const float* __restrict__ ln_g, const float* __restrict__ ln_b,
    const bf16_t* __restrict__ wqF, const float* __restrict__ bq,
    bf16_t* __restrict__ q_bf) {
  __shared__ __align__(16) bf16_t anorm[64][264];
  const int t = threadIdx.x, l = t & 63, w = t >> 6;
  const float4 g4 = *reinterpret_cast<const float4*>(ln_g + l * 4);
  const float4 b4 = *reinterpret_cast<const float4*>(ln_b + l * 4);
  float4 v[16];
  #pragma unroll
  for (int i = 0; i < 16; ++i)
    v[i] = *reinterpret_cast<const float4*>(h_in + (size_t)(w*16 + i) * 256 + l * 4);
  #pragma unroll
  for (int i = 0; i < 16; ++i) {
    float s1 = v[i].x + v[i].y + v[i].z + v[i].w;
    float s2 = v[i].x*v[i].x + v[i].y*v[i].y + v[i].z*v[i].z + v[i].w*v[i].w;
    #pragma unroll
    for (int msk = 1; msk < 64; msk <<= 1) { s1 += __shfl_xor(s1, msk); s2 += __shfl_xor(s2, msk); }
    const float mean = s1 * (1.f/256.f);
    const float rstd = rsqrtf(s2 * (1.f/256.f) - mean*mean + 1e-5f);
    bf16x4 pk;
    pk[0] = (bf16_t)((v[i].x - mean) * rstd * g4.x + b4.x);
    pk[1] = (bf16_t)((v[i].y - mean) * rstd * g4.y + b4.y);
    pk[2] = (bf16_t)((v[i].z - mean) * rstd * g4.z + b4.z);
    pk[3] = (bf16_t)((v[i].w - mean) * rstd * g4.w + b4.w);
    *reinterpret_cast<bf16x4*>(&anorm[w*16 + i][l*4]) = pk;
  }
  __syncthreads();
  const int l16 = l & 15, l4 = l >> 4;
  f32x4 acc[4][4] = {};
  for (int ks = 0; ks < 8; ++ks) {
    const int k = ks*32 + l4*8;
    bf16x8 a[4], b[4];
    #pragma unroll
    for (int mi = 0; mi < 4; ++mi) a[mi] = ld8(&anorm[mi*16 + l16][k]);
    #pragma unroll
    for (int ni = 0; ni < 4; ++ni) b[ni] = ld8(wqF + (((size_t)((w*4 + ni)*8 + ks)) << 9) + l*8);
    #pragma unroll
    for (int mi = 0; mi < 4; ++mi)
      #pragma unroll
      for (int ni = 0; ni < 4; ++ni) acc[mi][ni] = mfma16(a[mi], b[ni], acc[mi][ni]);
  }
  #pragma unroll
  for (int mi = 0; mi < 4; ++mi)
    #pragma unroll
    for (int ni = 0; ni < 4; ++ni) {
      const int d = w*64 + ni*16 + l16;
      const float bias = bq[d];
      bf16_t* outp = q_bf + (((size_t)(mi*8 + w*2 + (ni>>1))) << 9) + ((ni&1)*2 + (l16>>3))*128 + (l16&7);
      #pragma unroll
      for (int rr = 0; rr < 4; ++rr)
        outp[(l4*4 + rr)*8] = (bf16_t)((acc[mi][ni][rr] + bias) * 0.0625f);
    }
}

// ---------------------------------------------------------------------------
// K_logits: logits = q @ in_k^T (fragment layouts), fused softmax over slots.
// ---------------------------------------------------------------------------
__global__ __launch_bounds__(256) void k_logits(
    const bf16_t* __restrict__ q_bf, const bf16_t* __restrict__ in_kF,
    bf16_t* __restrict__ attnF, float* __restrict__ attn_f32, int write_f32) {
  const int t = threadIdx.x, l = t & 63, w = t >> 6, l16 = l & 15, l4 = l >> 4;
  const int m0 = blockIdx.x * 256 + w * 64;
  f32x4 acc[4][4] = {};
  for (int ks = 0; ks < 8; ++ks) {
    bf16x8 a[4], b[4];
    #pragma unroll
    for (int mi = 0; mi < 4; ++mi) a[mi] = ld8(q_bf + (((size_t)(mi*8 + ks)) << 9) + l*8);
    #pragma unroll
    for (int ni = 0; ni < 4; ++ni)
      b[ni] = ld8(in_kF + (((size_t)((blockIdx.x*16 + w*4 + ni)*8 + ks)) << 9) + l*8);
    #pragma unroll
    for (int mi = 0; mi < 4; ++mi)
      #pragma unroll
      for (int ni = 0; ni < 4; ++ni) acc[mi][ni] = mfma16(a[mi], b[ni], acc[mi][ni]);
  }
  #pragma unroll
  for (int ni = 0; ni < 4; ++ni) {
    float mx = -3.0e38f;
    #pragma unroll
    for (int mi = 0; mi < 4; ++mi)
      #pragma unroll
      for (int rr = 0; rr < 4; ++rr) mx = fmaxf(mx, acc[mi][ni][rr]);
    mx = fmaxf(mx, __shfl_xor(mx, 16));
    mx = fmaxf(mx, __shfl_xor(mx, 32));
    float sm = 0.f;
    #pragma unroll
    for (int mi = 0; mi < 4; ++mi)
      #pragma unroll
      for (int rr = 0; rr < 4; ++rr) {
        float ev = __expf(acc[mi][ni][rr] - mx);
        acc[mi][ni][rr] = ev; sm += ev;
      }
    sm += __shfl_xor(sm, 16);
    sm += __shfl_xor(sm, 32);
    const float inv = 1.0f / sm;
    #pragma unroll
    for (int mi = 0; mi < 4; ++mi)
      #pragma unroll
      for (int rr = 0; rr < 4; ++rr) acc[mi][ni][rr] *= inv;
  }
  #pragma unroll
  for (int mi = 0; mi < 4; ++mi)
    #pragma unroll
    for (int ni = 0; ni < 4; ++ni) {
      const int mc = blockIdx.x*8 + w*2 + (ni >> 1);
      bf16_t* outp = attnF + ((((size_t)mi)*2048 + mc) << 9) + ((ni&1)*2 + (l16>>3))*128 + (l16&7);
      #pragma unroll
      for (int rr = 0; rr < 4; ++rr) {
        outp[(l4*4 + rr)*8] = (bf16_t)acc[mi][ni][rr];
        if (write_f32) {
          const int s = mi*16 + l4*4 + rr;
          attn_f32[(size_t)s*65536 + (m0 + ni*16 + l16)] = acc[mi][ni][rr];
        }
      }
    }
}

// ---------------------------------------------------------------------------
// K_pv: split-K partial[c] = attn[:, chunk] @ v[chunk, :]  (chunk=512), bf16 out
// ---------------------------------------------------------------------------
__global__ __launch_bounds__(256) void k_pv(
    const bf16_t* __restrict__ attnF,
    const bf16_t* __restrict__ in_vF, const bf16_t* __restrict__ tgt_vF,
    bf16_t* __restrict__ p_in, bf16_t* __restrict__ p_tgt) {
  const int c = blockIdx.x, side = blockIdx.y;
  const bf16_t* V = side ? tgt_vF : in_vF;
  bf16_t* P = side ? p_tgt : p_in;
  const int t = threadIdx.x, l = t & 63, w = t >> 6, l16 = l & 15, l4 = l >> 4;
  f32x4 acc[4][4] = {};
  for (int ks = 0; ks < 16; ++ks) {
    const size_t mc = c*16 + ks;
    bf16x8 a[4], b[4];
    #pragma unroll
    for (int mi = 0; mi < 4; ++mi) a[mi] = ld8(attnF + ((((size_t)mi)*2048 + mc) << 9) + l*8);
    #pragma unroll
    for (int ni = 0; ni < 4; ++ni) b[ni] = ld8(V + ((((size_t)(w*4 + ni))*2048 + mc) << 9) + l*8);
    #pragma unroll
    for (int mi = 0; mi < 4; ++mi)
      #pragma unroll
      for (int ni = 0; ni < 4; ++ni) acc[mi][ni] = mfma16(a[mi], b[ni], acc[mi][ni]);
  }
  #pragma unroll
  for (int mi = 0; mi < 4; ++mi)
    #pragma unroll
    for (int ni = 0; ni < 4; ++ni) {
      const int d = w*64 + ni*16 + l16;
      #pragma unroll
      for (int rr = 0; rr < 4; ++rr) {
        const int s = mi*16 + l4*4 + rr;
        P[(size_t)c*16384 + s*256 + d] = (bf16_t)acc[mi][ni][rr];
      }
    }
}

// K_pvred: reduce 128 bf16 partials -> up (fragment layout)
__global__ __launch_bounds__(256) void k_pvred(
    const bf16_t* __restrict__ p_in, const bf16_t* __restrict__ p_tgt,
    bf16_t* __restrict__ upF) {
  const int b = blockIdx.x;
  const int side = b >> 6, s = b & 63;
  const int d = threadIdx.x;
  const bf16_t* P = (side ? p_tgt : p_in) + s*256 + d;
  float sum = 0.f;
  #pragma unroll 8
  for (int cc = 0; cc < 128; ++cc) sum += (float)P[(size_t)cc * 16384];
  upF[side*16384 + (((s>>4)*8 + (d>>5))<<9) + ((d>>3)&3)*128 + (s&15)*8 + (d&7)] = (bf16_t)sum;
}

// ---------------------------------------------------------------------------
// K_gates: gi = up @ Wih + bih ; gh = h @ Whh + bhh  (fragment layouts)
// ---------------------------------------------------------------------------
__global__ __launch_bounds__(256) void k_gates(
    const bf16_t* __restrict__ upF, const bf16_t* __restrict__ h_bf,
    const bf16_t* __restrict__ wihF_in, const bf16_t* __restrict__ whhF_in,
    const bf16_t* __restrict__ wihF_tgt, const bf16_t* __restrict__ whhF_tgt,
    const float* __restrict__ bih_in, const float* __restrict__ bhh_in,
    const float* __restrict__ bih_tgt, const float* __restrict__ bhh_tgt,
    float* __restrict__ gi, float* __restrict__ gh) {
  const int nchunk = blockIdx.x, which = blockIdx.y, side = blockIdx.z;
  const bf16_t* Aop = (which ? h_bf : upF) + side*16384;
  const bf16_t* WF = side ? (which ? whhF_tgt : wihF_tgt) : (which ? whhF_in : wihF_in);
  const float* bias = side ? (which ? bhh_tgt : bih_tgt) : (which ? bhh_in : bih_in);
  float* out = (which ? gh : gi) + side*49152;
  const int t = threadIdx.x, l = t & 63, w = t >> 6, l16 = l & 15, l4 = l >> 4;
  const int n0 = nchunk*256 + w*64;
  f32x4 acc[4][4] = {};
  for (int ks = 0; ks < 8; ++ks) {
    bf16x8 a[4], b[4];
    #pragma unroll
    for (int mi = 0; mi < 4; ++mi) a[mi] = ld8(Aop + (((size_t)(mi*8 + ks)) << 9) + l*8);
    #pragma unroll
    for (int ni = 0; ni < 4; ++ni)
      b[ni] = ld8(WF + (((size_t)((nchunk*16 + w*4 + ni)*8 + ks)) << 9) + l*8);
    #pragma unroll
    for (int mi = 0; mi < 4; ++mi)
      #pragma unroll
      for (int ni = 0; ni < 4; ++ni) acc[mi][ni] = mfma16(a[mi], b[ni], acc[mi][ni]);
  }
  #pragma unroll
  for (int mi = 0; mi < 4; ++mi)
    #pragma unroll
    for (int ni = 0; ni < 4; ++ni) {
      const int n = n0 + ni*16 + l16;
      const float bb = bias[n];
      #pragma unroll
      for (int rr = 0; rr < 4; ++rr) {
        const int s = mi*16 + l4*4 + rr;
        out[(size_t)s*768 + n] = acc[mi][ni][rr] + bb;
      }
    }
}

// ---------------------------------------------------------------------------
// K_gru_ln: GRUCell elementwise + LN -> hp_f32 (row-major), hpn (fragment)
// ---------------------------------------------------------------------------
__global__ __launch_bounds__(256) void k_gru_ln(
    const float* __restrict__ gi, const float* __restrict__ gh,
    const float* __restrict__ h_f32,
    const float* __restrict__ ln_mi_g, const float* __restrict__ ln_mi_b,
    const float* __restrict__ ln_mt_g, const float* __restrict__ ln_mt_b,
    float* __restrict__ hp_f32, bf16_t* __restrict__ hpnF) {
  const int s = blockIdx.x, side = blockIdx.y;
  const int d = threadIdx.x;
  const float* GI = gi + side*49152 + s*768;
  const float* GH = gh + side*49152 + s*768;
  const float hv = h_f32[side*16384 + s*256 + d];
  const float rg = 1.f / (1.f + __expf(-(GI[d] + GH[d])));
  const float zg = 1.f / (1.f + __expf(-(GI[256 + d] + GH[256 + d])));
  const float ng = tanhf(GI[512 + d] + rg * GH[512 + d]);
  const float hp = (1.f - zg) * ng + zg * hv;
  float a = hp, b2 = hp * hp;
  #pragma unroll
  for (int msk = 1; msk < 64; msk <<= 1) { a += __shfl_xor(a, msk); b2 += __shfl_xor(b2, msk); }
  __shared__ float reda[4], redb[4];
  const int w = d >> 6, lid = d & 63;
  if (lid == 0) { reda[w] = a; redb[w] = b2; }
  __syncthreads();
  const float S1 = reda[0] + reda[1] + reda[2] + reda[3];
  const float S2 = redb[0] + redb[1] + redb[2] + redb[3];
  const float mean = S1 * (1.f/256.f);
  const float rstd = rsqrtf(S2 * (1.f/256.f) - mean*mean + 1e-5f);
  const float* g = side ? ln_mt_g : ln_mi_g;
  const float* bb = side ? ln_mt_b : ln_mi_b;
  const float nv = (hp - mean) * rstd * g[d] + bb[d];
  hp_f32[side*16384 + s*256 + d] = hp;
  hpnF[side*16384 + (((s>>4)*8 + (d>>5))<<9) + ((d>>3)&3)*128 + (s&15)*8 + (d&7)] = (bf16_t)nv;
}

// ---------------------------------------------------------------------------
// K_mlpq: fused  hidden=relu(hpn@W1+b1) ; h_new=hp+hidden@W2+b2 ;
//         (side0, make_q) q = bf16((LN(h_new)@Wq+bq)/16)
// ---------------------------------------------------------------------------
__global__ __launch_bounds__(256) void k_mlpq(
    const bf16_t* __restrict__ hpnF,
    const bf16_t* __restrict__ w1F_in, const bf16_t* __restrict__ w1F_tgt,
    const float* __restrict__ b1_in, const float* __restrict__ b1_tgt,
    const bf16_t* __restrict__ w2F_in, const bf16_t* __restrict__ w2F_tgt,
    const float* __restrict__ b2_in, const float* __restrict__ b2_tgt,
    const float* __restrict__ hp_f32,
    float* __restrict__ h_f32, bf16_t* __restrict__ h_bf, float* __restrict__ slots_out,
    const float* __restrict__ ln_sg, const float* __restrict__ ln_sb,
    const bf16_t* __restrict__ wqF, const float* __restrict__ bq,
    bf16_t* __restrict__ q_bf, int make_q) {
  const int side = blockIdx.x;
  __shared__ __align__(16) bf16_t hid[64][264];
  const int t = threadIdx.x, l = t & 63, w = t >> 6, l16 = l & 15, l4 = l >> 4;
  const int NH = side ? 256 : 128;
  {  // GEMM1
    const bf16_t* Aop = hpnF + side*16384;
    const bf16_t* WF = side ? w1F_tgt : w1F_in;
    const float* b1 = side ? b1_tgt : b1_in;
    const int ntiles = NH >> 6;
    for (int nt = 0; nt < ntiles; ++nt) {
      const int n0 = w*(NH>>2) + nt*16;
      f32x4 acc[4] = {};
      for (int ks = 0; ks < 8; ++ks) {
        bf16x8 b = ld8(WF + (((size_t)((n0>>4)*8 + ks)) << 9) + l*8);
        #pragma unroll
        for (int mt = 0; mt < 4; ++mt)
          acc[mt] = mfma16(ld8(Aop + (((size_t)(mt*8 + ks)) << 9) + l*8), b, acc[mt]);
      }
      const float bb = b1[n0 + l16];
      #pragma unroll
      for (int mt = 0; mt < 4; ++mt)
        #pragma unroll
        for (int rr = 0; rr < 4; ++rr) {
          const int s = mt*16 + l4*4 + rr;
          hid[s][n0 + l16] = (bf16_t)fmaxf(acc[mt][rr] + bb, 0.f);
        }
    }
  }
  __syncthreads();
  {  // GEMM2
    const bf16_t* WF = side ? w2F_tgt : w2F_in;
    const float* b2 = side ? b2_tgt : b2_in;
    const int ksteps = NH >> 5;
    #pragma unroll
    for (int nt = 0; nt < 4; ++nt) {
      const int n0 = w*64 + nt*16;
      f32x4 acc[4] = {};
      for (int ks = 0; ks < ksteps; ++ks) {
        const int k = ks*32 + l4*8;
        bf16x8 b = ld8(WF + (((size_t)((n0>>4)*ksteps + ks)) << 9) + l*8);
        #pragma unroll
        for (int mt = 0; mt < 4; ++mt)
          acc[mt] = mfma16(ld8(&hid[mt*16 + l16][k]), b, acc[mt]);
      }
      const int n = n0 + l16;
      const float bb = b2[n];
      #pragma unroll
      for (int mt = 0; mt < 4; ++mt)
        #pragma unroll
        for (int rr = 0; rr < 4; ++rr) {
          const int s = mt*16 + l4*4 + rr;
          const int idx = side*16384 + s*256 + n;
          const float val = acc[mt][rr] + bb + hp_f32[idx];
          h_f32[idx] = val;
          slots_out[idx] = val;
          h_bf[side*16384 + (((s>>4)*8 + (n>>5))<<9) + ((n>>3)&3)*128 + (s&15)*8 + (n&7)] = (bf16_t)val;
        }
    }
  }
  if (!make_q || side != 0) return;
  __syncthreads();
  {  // LN(h_new) -> hid
    for (int i = 0; i < 16; ++i) {
      const int s = w*16 + i;
      float4 x = *reinterpret_cast<const float4*>(h_f32 + s*256 + 4*l);
      float a = x.x + x.y + x.z + x.w;
      float b2s = x.x*x.x + x.y*x.y + x.z*x.z + x.w*x.w;
      #pragma unroll
      for (int msk = 1; msk < 64; msk <<= 1) { a += __shfl_xor(a, msk); b2s += __shfl_xor(b2s, msk); }
      const float mean = a * (1.f/256.f);
      const float rstd = rsqrtf(b2s * (1.f/256.f) - mean*mean + 1e-5f);
      float4 g4 = *reinterpret_cast<const float4*>(ln_sg + 4*l);
      float4 bb4 = *reinterpret_cast<const float4*>(ln_sb + 4*l);
      bf16x4 pk;
      pk[0] = (bf16_t)((x.x - mean) * rstd * g4.x + bb4.x);
      pk[1] = (bf16_t)((x.y - mean) * rstd * g4.y + bb4.y);
      pk[2] = (bf16_t)((x.z - mean) * rstd * g4.z + bb4.z);
      pk[3] = (bf16_t)((x.w - mean) * rstd * g4.w + bb4.w);
      *reinterpret_cast<bf16x4*>(&hid[s][4*l]) = pk;
    }
  }
  __syncthreads();
  {  // q GEMM
    #pragma unroll
    for (int nt = 0; nt < 4; ++nt) {
      const int n0 = w*64 + nt*16;
      f32x4 acc[4] = {};
      for (int ks = 0; ks < 8; ++ks) {
        const int k = ks*32 + l4*8;
        bf16x8 b = ld8(wqF + (((size_t)((n0>>4)*8 + ks)) << 9) + l*8);
        #pragma unroll
        for (int mt = 0; mt < 4; ++mt)
          acc[mt] = mfma16(ld8(&hid[mt*16 + l16][k]), b, acc[mt]);
      }
      const int d = n0 + l16;
      const float bb = bq[d];
      #pragma unroll
      for (int mt = 0; mt < 4; ++mt) {
        bf16_t* op = q_bf + (((size_t)(mt*8 + (d>>5))) << 9) + ((d>>3)&3)*128 + (d&7);
        #pragma unroll
        for (int rr = 0; rr < 4; ++rr)
          op[(l4*4 + rr)*8] = (bf16_t)((acc[mt][rr] + bb) * 0.0625f);
      }
    }
  }
}

// ---------------------------------------------------------------------------
extern "C" void kernel_launch(void* const* d_in, const int* in_sizes, int n_in,
                              void* d_out, int out_size, void* d_ws, size_t ws_size,
                              hipStream_t stream) {
  (void)in_sizes; (void)n_in; (void)out_size;
  const float* inputs     = (const float*)d_in[0];
  const float* target     = (const float*)d_in[1];
  const float* in_slots   = (const float*)d_in[2];
  const float* tgt_slots  = (const float*)d_in[3];
  const float* ln_in_g    = (const float*)d_in[4];
  const float* ln_in_b    = (const float*)d_in[5];
  const float* ln_tgt_g   = (const float*)d_in[6];
  const float* ln_tgt_b   = (const float*)d_in[7];
  const float* Wk  = (const float*)d_in[8];
  const float* bk  = (const float*)d_in[9];
  const float* Wv  = (const float*)d_in[10];
  const float* bv  = (const float*)d_in[11];
  const float* Wvt = (const float*)d_in[12];
  const float* bvt = (const float*)d_in[13];
  const float* ln_slots_g = (const float*)d_in[14];
  const float* ln_slots_b = (const float*)d_in[15];
  const float* Wq  = (const float*)d_in[16];
  const float* bq  = (const float*)d_in[17];
  const float* gru_in_Wih  = (const float*)d_in[18];
  const float* gru_in_Whh  = (const float*)d_in[19];
  const float* gru_in_bih  = (const float*)d_in[20];
  const float* gru_in_bhh  = (const float*)d_in[21];
  const float* gru_tgt_Wih = (const float*)d_in[22];
  const float* gru_tgt_Whh = (const float*)d_in[23];
  const float* gru_tgt_bih = (const float*)d_in[24];
  const float* gru_tgt_bhh = (const float*)d_in[25];
  const float* ln_mi_g = (const float*)d_in[26];
  const float* ln_mi_b = (const float*)d_in[27];
  const float* mi_W1 = (const float*)d_in[28];
  const float* mi_b1 = (const float*)d_in[29];
  const float* mi_W2 = (const float*)d_in[30];
  const float* mi_b2 = (const float*)d_in[31];
  const float* ln_mt_g = (const float*)d_in[32];
  const float* ln_mt_b = (const float*)d_in[33];
  const float* mt_W1 = (const float*)d_in[34];
  const float* mt_b1 = (const float*)d_in[35];
  const float* mt_W2 = (const float*)d_in[36];
  const float* mt_b2 = (const float*)d_in[37];

  char* ws = (char*)d_ws;
  bf16_t* wt      = (bf16_t*)(ws);
  bf16_t* in_kF   = (bf16_t*)(ws + 2490368ull);
  bf16_t* in_vF   = (bf16_t*)(ws + 36044800ull);
  bf16_t* tgt_vF  = (bf16_t*)(ws + 69599232ull);
  bf16_t* attnF   = (bf16_t*)(ws + 103153664ull);
  bf16_t* q_bf    = (bf16_t*)(ws + 111542272ull);
  bf16_t* h_bf    = (bf16_t*)(ws + 111575040ull);
  bf16_t* upF     = (bf16_t*)(ws + 111640576ull);
  bf16_t* hpnF    = (bf16_t*)(ws + 111673344ull);
  float*  h_f32   = (float*)(ws + 111706112ull);
  float*  hp_f32  = (float*)(ws + 111837184ull);
  float*  gi      = (float*)(ws + 111968256ull);
  float*  gh      = (float*)(ws + 112361472ull);
  bf16_t* p_in    = (bf16_t*)(ws + 112754688ull);
  bf16_t* p_tgt   = (bf16_t*)(ws + 116948992ull);       // end 121,143,296
  bf16_t* anormF  = (bf16_t*)(ws + 121143296ull);       // 67,108,864 B (split path)
  const bool use_split = ws_size >= 188252160ull;

  bf16_t* wkF = wt;
  bf16_t* wvF = wt + 65536;
  bf16_t* wvtF = wt + 131072;
  bf16_t* wqF = wt + 196608;
  bf16_t* wihF_in  = wt + 262144;
  bf16_t* whhF_in  = wt + 458752;
  bf16_t* wihF_tgt = wt + 655360;
  bf16_t* whhF_tgt = wt + 851968;
  bf16_t* w1F_in  = wt + 1048576;
  bf16_t* w2F_in  = wt + 1081344;
  bf16_t* w1F_tgt = wt + 1114112;
  bf16_t* w2F_tgt = wt + 1179648;

  float* attn_out = (float*)d_out + 32768;

  WtArgs wa = {Wk, Wv, Wvt, Wq, gru_in_Wih, gru_in_Whh, gru_tgt_Wih, gru_tgt_Whh,
               mi_W1, mi_W2, mt_W1, mt_W2};
  k_wtrans<<<dim3(48, 12), 256, 0, stream>>>(wa, wt);
  k_init<<<128, 256, 0, stream>>>(in_slots, tgt_slots, h_f32, h_bf);
  if (use_split) {
    k_ln<<<2048, 256, 0, stream>>>(inputs, target, ln_in_g, ln_in_b,
        ln_tgt_g, ln_tgt_b, anormF);
    k_proj<<<dim3(1024, 2), 256, 0, stream>>>(anormF, wkF, wvF, wvtF,
        bk, bv, bvt, in_kF, in_vF, tgt_vF);
  } else {
    k_phaseA<<<dim3(1024, 2), 256, 0, stream>>>(inputs, target, ln_in_g, ln_in_b,
        ln_tgt_g, ln_tgt_b, wkF, wvF, wvtF, bk, bv, bvt, in_kF, in_vF, tgt_vF);
  }
  k_q<<<1, 256, 0, stream>>>(h_f32, ln_slots_g, ln_slots_b, wqF, bq, q_bf);

  for (int it = 0; it < 3; ++it) {
    k_logits<<<256, 256, 0, stream>>>(q_bf, in_kF, attnF, attn_out, it == 2 ? 1 : 0);
    k_pv<<<dim3(128, 2), 256, 0, stream>>>(attnF, in_vF, tgt_vF, p_in, p_tgt);
    k_pvred<<<128, 256, 0, stream>>>(p_in, p_tgt, upF);
    k_gates<<<dim3(3, 2, 2), 256, 0, stream>>>(upF, h_bf, wihF_in, whhF_in,
        wihF_tgt, whhF_tgt, gru_in_bih, gru_in_bhh, gru_tgt_bih, gru_tgt_bhh, gi, gh);
    k_gru_ln<<<dim3(64, 2), 256, 0, stream>>>(gi, gh, h_f32, ln_mi_g, ln_mi_b,
        ln_mt_g, ln_mt_b, hp_f32, hpnF);
    k_mlpq<<<2, 256, 0, stream>>>(hpnF, w1F_in, w1F_tgt, mi_b1, mt_b1,
        w2F_in, w2F_tgt, mi_b2, mt_b2, hp_f32, h_f32, h_bf, (float*)d_out,
        ln_slots_g, ln_slots_b, wqF, bq, q_bf, it < 2 ? 1 : 0);
  }
}

// Round 5
// 313.273 us; speedup vs baseline: 1.3649x; 1.3649x over previous
//
#include <hip/hip_runtime.h>
#include <hip/hip_bf16.h>
#include <math.h>

typedef __bf16 bf16_t;
typedef __bf16 bf16x8 __attribute__((ext_vector_type(8)));
typedef __bf16 bf16x4 __attribute__((ext_vector_type(4)));
typedef float f32x4 __attribute__((ext_vector_type(4)));

#define DEVI __device__ __forceinline__

DEVI f32x4 mfma16(bf16x8 a, bf16x8 b, f32x4 c) {
  return __builtin_amdgcn_mfma_f32_16x16x32_bf16(a, b, c, 0, 0, 0);
}
DEVI bf16x8 ld8(const bf16_t* p) { return *reinterpret_cast<const bf16x8*>(p); }

// Fragment layout: element (row, k) of an MFMA A/B operand matrix lives at
//   ((row>>4)*(K/32) + (k>>5))*512 + ((k>>3)&3)*128 + (row&15)*8 + (k&7)
// Consumer lane l of (rowtile, kchunk) reads 8 contiguous bf16 at
//   ((rowtile*(K/32)+kchunk)<<9) + l*8.
// Producer flush identity: region_inner_offset(lane l) == l*8  (16 B/lane).

// ---------------------------------------------------------------------------
// K0: tiled transpose + bf16 convert + FRAGMENT swizzle of all weights.
// ---------------------------------------------------------------------------
struct WtArgs { const float* s0; const float* s1; const float* s2; const float* s3;
                const float* s4; const float* s5; const float* s6; const float* s7;
                const float* s8; const float* s9; const float* s10; const float* s11; };

__global__ __launch_bounds__(256) void k_wtrans(WtArgs A, bf16_t* __restrict__ wt) {
  constexpr int offs[12] = {0,65536,131072,196608,262144,458752,655360,851968,
                            1048576,1081344,1114112,1179648};
  constexpr int Ks[12]   = {256,256,256,256,256,256,256,256,256,128,256,256};
  constexpr int Ns[12]   = {256,256,256,256,768,768,768,768,128,256,256,256};
  const int m = blockIdx.y;
  const int K = Ks[m], N = Ns[m];
  const int tn = N >> 6;
  const int tile = blockIdx.x;
  if (tile >= (K >> 6) * tn) return;
  const int tk = tile / tn, tc = tile - tk * tn;
  const float* sp;
  switch (m) {
    case 0: sp = A.s0; break; case 1: sp = A.s1; break; case 2: sp = A.s2; break;
    case 3: sp = A.s3; break; case 4: sp = A.s4; break; case 5: sp = A.s5; break;
    case 6: sp = A.s6; break; case 7: sp = A.s7; break; case 8: sp = A.s8; break;
    case 9: sp = A.s9; break; case 10: sp = A.s10; break; default: sp = A.s11; break;
  }
  __shared__ float ts[64][65];
  const int t = threadIdx.x;
  const int k0 = tk * 64, n0 = tc * 64;
  {
    const int c = t & 63, rq = t >> 6;
    #pragma unroll
    for (int i = 0; i < 16; ++i) {
      const int r = rq * 16 + i;
      ts[r][c] = sp[(size_t)(k0 + r) * N + n0 + c];
    }
  }
  __syncthreads();
  bf16_t* dst = wt + offs[m];
  const int n_l = t & 63, kq = t >> 6;
  #pragma unroll
  for (int h = 0; h < 2; ++h) {
    const int k_l = kq * 16 + h * 8;
    bf16x8 pk;
    #pragma unroll
    for (int e = 0; e < 8; ++e) pk[e] = (bf16_t)ts[k_l + e][n_l];
    const int n_g = n0 + n_l, k_g = k0 + k_l;
    const int nt = n_g >> 4, kc = k_g >> 5;
    const int lane = (((k_g >> 3) & 3) << 4) + (n_g & 15);
    *reinterpret_cast<bf16x8*>(dst + (((size_t)(nt * (K >> 5) + kc)) << 9) + lane * 8) = pk;
  }
}

// ---------------------------------------------------------------------------
// K_init: slots f32 -> h_f32 (row-major) / h_bf (fragment layout)
// ---------------------------------------------------------------------------
__global__ __launch_bounds__(256) void k_init(const float* __restrict__ in_slots,
                                              const float* __restrict__ tgt_slots,
                                              float* __restrict__ h_f32,
                                              bf16_t* __restrict__ h_bf) {
  int idx = blockIdx.x * 256 + threadIdx.x;
  int side = idx >> 14, j = idx & 16383;
  int s = j >> 8, d = j & 255;
  float x = (side ? tgt_slots : in_slots)[j];
  h_f32[idx] = x;
  h_bf[side*16384 + (((s>>4)*8 + (d>>5))<<9) + ((d>>3)&3)*128 + (s&15)*8 + (d&7)] = (bf16_t)x;
}

// ---------------------------------------------------------------------------
// Phase A (fused): LN(rows) then projections, LDS-staged coalesced C-stores.
// ---------------------------------------------------------------------------
__global__ __launch_bounds__(256) void k_phaseA(
    const float* __restrict__ inputs, const float* __restrict__ target,
    const float* __restrict__ ln_in_g, const float* __restrict__ ln_in_b,
    const float* __restrict__ ln_tgt_g, const float* __restrict__ ln_tgt_b,
    const bf16_t* __restrict__ wkF, const bf16_t* __restrict__ wvF, const bf16_t* __restrict__ wvtF,
    const float* __restrict__ bk, const float* __restrict__ bv, const float* __restrict__ bvt,
    bf16_t* __restrict__ in_kF, bf16_t* __restrict__ in_vF, bf16_t* __restrict__ tgt_vF) {
  const int side = blockIdx.y;
  const int m0 = blockIdx.x * 64;
  const int t = threadIdx.x, l = t & 63, w = t >> 6;
  __shared__ __align__(16) bf16_t anorm[64][264];
  __shared__ __align__(16) bf16_t stg[4][64][68];   // per-wave C-store staging
  const float* src = side ? target : inputs;
  const float* gp = side ? ln_tgt_g : ln_in_g;
  const float* bp = side ? ln_tgt_b : ln_in_b;
  const float4 g4 = *reinterpret_cast<const float4*>(gp + l * 4);
  const float4 b4 = *reinterpret_cast<const float4*>(bp + l * 4);
  float4 v[16];
  #pragma unroll
  for (int i = 0; i < 16; ++i)
    v[i] = *reinterpret_cast<const float4*>(src + (size_t)(m0 + w*16 + i) * 256 + l * 4);
  #pragma unroll
  for (int i = 0; i < 16; ++i) {
    float s1 = v[i].x + v[i].y + v[i].z + v[i].w;
    float s2 = v[i].x*v[i].x + v[i].y*v[i].y + v[i].z*v[i].z + v[i].w*v[i].w;
    #pragma unroll
    for (int msk = 1; msk < 64; msk <<= 1) { s1 += __shfl_xor(s1, msk); s2 += __shfl_xor(s2, msk); }
    const float mean = s1 * (1.f/256.f);
    const float rstd = rsqrtf(s2 * (1.f/256.f) - mean*mean + 1e-5f);
    bf16x4 pk;
    pk[0] = (bf16_t)((v[i].x - mean) * rstd * g4.x + b4.x);
    pk[1] = (bf16_t)((v[i].y - mean) * rstd * g4.y + b4.y);
    pk[2] = (bf16_t)((v[i].z - mean) * rstd * g4.z + b4.z);
    pk[3] = (bf16_t)((v[i].w - mean) * rstd * g4.w + b4.w);
    *reinterpret_cast<bf16x4*>(&anorm[w*16 + i][l*4]) = pk;
  }
  __syncthreads();
  const int l16 = l & 15, l4 = l >> 4;

  if (side == 0) {  // C1 = anorm @ Wk -> in_kF (fragment rows=m, depth=d)
    f32x4 acc[4][4] = {};
    for (int ks = 0; ks < 8; ++ks) {
      const int k = ks*32 + l4*8;
      bf16x8 a[4], b[4];
      #pragma unroll
      for (int mi = 0; mi < 4; ++mi) a[mi] = ld8(&anorm[mi*16 + l16][k]);
      #pragma unroll
      for (int ni = 0; ni < 4; ++ni) b[ni] = ld8(wkF + (((size_t)((w*4 + ni)*8 + ks)) << 9) + l*8);
      #pragma unroll
      for (int mi = 0; mi < 4; ++mi)
        #pragma unroll
        for (int ni = 0; ni < 4; ++ni) acc[mi][ni] = mfma16(a[mi], b[ni], acc[mi][ni]);
    }
    #pragma unroll
    for (int mi = 0; mi < 4; ++mi)
      #pragma unroll
      for (int ni = 0; ni < 4; ++ni) {
        const int d = w*64 + ni*16 + l16;
        const float bias = bk[d];
        #pragma unroll
        for (int rr = 0; rr < 4; ++rr)
          stg[w][mi*16 + l4*4 + rr][ni*16 + l16] = (bf16_t)(acc[mi][ni][rr] + bias);
      }
    #pragma unroll
    for (int mi = 0; mi < 4; ++mi)
      #pragma unroll
      for (int kc = 0; kc < 2; ++kc) {
        bf16x8 vv = *reinterpret_cast<const bf16x8*>(&stg[w][mi*16 + l16][kc*32 + l4*8]);
        *reinterpret_cast<bf16x8*>(in_kF +
            ((((size_t)(blockIdx.x*4 + mi))*8 + (w*2 + kc)) << 9) + l*8) = vv;
      }
  }
  {  // C2 = W(as A) @ anorm^T(as B) -> vF (fragment rows=d, depth=m)
    const bf16_t* WF = side ? wvtF : wvF;
    const float* bias = side ? bvt : bv;
    bf16_t* out = side ? tgt_vF : in_vF;
    f32x4 acc[4][4] = {};
    for (int ks = 0; ks < 8; ++ks) {
      const int k = ks*32 + l4*8;
      bf16x8 a[4], b[4];
      #pragma unroll
      for (int mi = 0; mi < 4; ++mi) a[mi] = ld8(WF + (((size_t)((w*4 + mi)*8 + ks)) << 9) + l*8);
      #pragma unroll
      for (int ni = 0; ni < 4; ++ni) b[ni] = ld8(&anorm[ni*16 + l16][k]);
      #pragma unroll
      for (int mi = 0; mi < 4; ++mi)
        #pragma unroll
        for (int ni = 0; ni < 4; ++ni) acc[mi][ni] = mfma16(a[mi], b[ni], acc[mi][ni]);
    }
    #pragma unroll
    for (int mi = 0; mi < 4; ++mi)
      #pragma unroll
      for (int ni = 0; ni < 4; ++ni)
        #pragma unroll
        for (int rr = 0; rr < 4; ++rr) {
          const int d = w*64 + mi*16 + l4*4 + rr;
          stg[w][mi*16 + l4*4 + rr][ni*16 + l16] = (bf16_t)(acc[mi][ni][rr] + bias[d]);
        }
    #pragma unroll
    for (int mi = 0; mi < 4; ++mi)
      #pragma unroll
      for (int mc = 0; mc < 2; ++mc) {
        bf16x8 vv = *reinterpret_cast<const bf16x8*>(&stg[w][mi*16 + l16][mc*32 + l4*8]);
        *reinterpret_cast<bf16x8*>(out +
            ((((size_t)(w*4 + mi))*2048 + (blockIdx.x*2 + mc)) << 9) + l*8) = vv;
      }
  }
}

// ---------------------------------------------------------------------------
// K_q: q (fragment layout) = bf16( (LN(in_slots) @ Wq + bq) / 16 ) — 1 block
// ---------------------------------------------------------------------------
__global__ __launch_bounds__(256) void k_q(
    const float* __restrict__ h_in,
    const float* __restrict__ ln_g, const float* __restrict__ ln_b,
    const bf16_t* __restrict__ wqF, const float* __restrict__ bq,
    bf16_t* __restrict__ q_bf) {
  __shared__ __align__(16) bf16_t anorm[64][264];
  const int t = threadIdx.x, l = t & 63, w = t >> 6;
  const float4 g4 = *reinterpret_cast<const float4*>(ln_g + l * 4);
  const float4 b4 = *reinterpret_cast<const float4*>(ln_b + l * 4);
  float4 v[16];
  #pragma unroll
  for (int i = 0; i < 16; ++i)
    v[i] = *reinterpret_cast<const float4*>(h_in + (size_t)(w*16 + i) * 256 + l * 4);
  #pragma unroll
  for (int i = 0; i < 16; ++i) {
    float s1 = v[i].x + v[i].y + v[i].z + v[i].w;
    float s2 = v[i].x*v[i].x + v[i].y*v[i].y + v[i].z*v[i].z + v[i].w*v[i].w;
    #pragma unroll
    for (int msk = 1; msk < 64; msk <<= 1) { s1 += __shfl_xor(s1, msk); s2 += __shfl_xor(s2, msk); }
    const float mean = s1 * (1.f/256.f);
    const float rstd = rsqrtf(s2 * (1.f/256.f) - mean*mean + 1e-5f);
    bf16x4 pk;
    pk[0] = (bf16_t)((v[i].x - mean) * rstd * g4.x + b4.x);
    pk[1] = (bf16_t)((v[i].y - mean) * rstd * g4.y + b4.y);
    pk[2] = (bf16_t)((v[i].z - mean) * rstd * g4.z + b4.z);
    pk[3] = (bf16_t)((v[i].w - mean) * rstd * g4.w + b4.w);
    *reinterpret_cast<bf16x4*>(&anorm[w*16 + i][l*4]) = pk;
  }
  __syncthreads();
  const int l16 = l & 15, l4 = l >> 4;
  f32x4 acc[4][4] = {};
  for (int ks = 0; ks < 8; ++ks) {
    const int k = ks*32 + l4*8;
    bf16x8 a[4], b[4];
    #pragma unroll
    for (int mi = 0; mi < 4; ++mi) a[mi] = ld8(&anorm[mi*16 + l16][k]);
    #pragma unroll
    for (int ni = 0; ni < 4; ++ni) b[ni] = ld8(wqF + (((size_t)((w*4 + ni)*8 + ks)) << 9) + l*8);
    #pragma unroll
    for (int mi = 0; mi < 4; ++mi)
      #pragma unroll
      for (int ni = 0; ni < 4; ++ni) acc[mi][ni] = mfma16(a[mi], b[ni], acc[mi][ni]);
  }
  #pragma unroll
  for (int mi = 0; mi < 4; ++mi)
    #pragma unroll
    for (int ni = 0; ni < 4; ++ni) {
      const int d = w*64 + ni*16 + l16;
      const float bias = bq[d];
      bf16_t* outp = q_bf + (((size_t)(mi*8 + w*2 + (ni>>1))) << 9) + ((ni&1)*2 + (l16>>3))*128 + (l16&7);
      #pragma unroll
      for (int rr = 0; rr < 4; ++rr)
        outp[(l4*4 + rr)*8] = (bf16_t)((acc[mi][ni][rr] + bias) * 0.0625f);
    }
}

// ---------------------------------------------------------------------------
// K_logits: logits = q @ in_k^T, fused softmax over slots; LDS-staged stores.
// ---------------------------------------------------------------------------
__global__ __launch_bounds__(256) void k_logits(
    const bf16_t* __restrict__ q_bf, const bf16_t* __restrict__ in_kF,
    bf16_t* __restrict__ attnF, float* __restrict__ attn_f32, int write_f32) {
  __shared__ __align__(16) bf16_t stg[4][64][68];
  const int t = threadIdx.x, l = t & 63, w = t >> 6, l16 = l & 15, l4 = l >> 4;
  const int m0 = blockIdx.x * 256 + w * 64;
  f32x4 acc[4][4] = {};
  for (int ks = 0; ks < 8; ++ks) {
    bf16x8 a[4], b[4];
    #pragma unroll
    for (int mi = 0; mi < 4; ++mi) a[mi] = ld8(q_bf + (((size_t)(mi*8 + ks)) << 9) + l*8);
    #pragma unroll
    for (int ni = 0; ni < 4; ++ni)
      b[ni] = ld8(in_kF + (((size_t)((blockIdx.x*16 + w*4 + ni)*8 + ks)) << 9) + l*8);
    #pragma unroll
    for (int mi = 0; mi < 4; ++mi)
      #pragma unroll
      for (int ni = 0; ni < 4; ++ni) acc[mi][ni] = mfma16(a[mi], b[ni], acc[mi][ni]);
  }
  #pragma unroll
  for (int ni = 0; ni < 4; ++ni) {
    float mx = -3.0e38f;
    #pragma unroll
    for (int mi = 0; mi < 4; ++mi)
      #pragma unroll
      for (int rr = 0; rr < 4; ++rr) mx = fmaxf(mx, acc[mi][ni][rr]);
    mx = fmaxf(mx, __shfl_xor(mx, 16));
    mx = fmaxf(mx, __shfl_xor(mx, 32));
    float sm = 0.f;
    #pragma unroll
    for (int mi = 0; mi < 4; ++mi)
      #pragma unroll
      for (int rr = 0; rr < 4; ++rr) {
        float ev = __expf(acc[mi][ni][rr] - mx);
        acc[mi][ni][rr] = ev; sm += ev;
      }
    sm += __shfl_xor(sm, 16);
    sm += __shfl_xor(sm, 32);
    const float inv = 1.0f / sm;
    #pragma unroll
    for (int mi = 0; mi < 4; ++mi)
      #pragma unroll
      for (int rr = 0; rr < 4; ++rr) acc[mi][ni][rr] *= inv;
  }
  #pragma unroll
  for (int mi = 0; mi < 4; ++mi)
    #pragma unroll
    for (int ni = 0; ni < 4; ++ni)
      #pragma unroll
      for (int rr = 0; rr < 4; ++rr) {
        stg[w][mi*16 + l4*4 + rr][ni*16 + l16] = (bf16_t)acc[mi][ni][rr];
        if (write_f32) {
          const int s = mi*16 + l4*4 + rr;
          attn_f32[(size_t)s*65536 + (m0 + ni*16 + l16)] = acc[mi][ni][rr];
        }
      }
  #pragma unroll
  for (int mi = 0; mi < 4; ++mi)
    #pragma unroll
    for (int mc = 0; mc < 2; ++mc) {
      bf16x8 vv = *reinterpret_cast<const bf16x8*>(&stg[w][mi*16 + l16][mc*32 + l4*8]);
      *reinterpret_cast<bf16x8*>(attnF +
          ((((size_t)mi)*2048 + (blockIdx.x*8 + w*2 + mc)) << 9) + l*8) = vv;
    }
}

// ---------------------------------------------------------------------------
// K_pv: split-K partial[c] = attn[:, chunk] @ v[chunk, :]  (chunk=512), bf16 out
// ---------------------------------------------------------------------------
__global__ __launch_bounds__(256) void k_pv(
    const bf16_t* __restrict__ attnF,
    const bf16_t* __restrict__ in_vF, const bf16_t* __restrict__ tgt_vF,
    bf16_t* __restrict__ p_in, bf16_t* __restrict__ p_tgt) {
  const int c = blockIdx.x, side = blockIdx.y;
  const bf16_t* V = side ? tgt_vF : in_vF;
  bf16_t* P = side ? p_tgt : p_in;
  const int t = threadIdx.x, l = t & 63, w = t >> 6, l16 = l & 15, l4 = l >> 4;
  f32x4 acc[4][4] = {};
  for (int ks = 0; ks < 16; ++ks) {
    const size_t mc = c*16 + ks;
    bf16x8 a[4], b[4];
    #pragma unroll
    for (int mi = 0; mi < 4; ++mi) a[mi] = ld8(attnF + ((((size_t)mi)*2048 + mc) << 9) + l*8);
    #pragma unroll
    for (int ni = 0; ni < 4; ++ni) b[ni] = ld8(V + ((((size_t)(w*4 + ni))*2048 + mc) << 9) + l*8);
    #pragma unroll
    for (int mi = 0; mi < 4; ++mi)
      #pragma unroll
      for (int ni = 0; ni < 4; ++ni) acc[mi][ni] = mfma16(a[mi], b[ni], acc[mi][ni]);
  }
  #pragma unroll
  for (int mi = 0; mi < 4; ++mi)
    #pragma unroll
    for (int ni = 0; ni < 4; ++ni) {
      const int d = w*64 + ni*16 + l16;
      #pragma unroll
      for (int rr = 0; rr < 4; ++rr) {
        const int s = mi*16 + l4*4 + rr;
        P[(size_t)c*16384 + s*256 + d] = (bf16_t)acc[mi][ni][rr];
      }
    }
}

// K_pvred: reduce 128 bf16 partials -> up (fragment layout)
__global__ __launch_bounds__(256) void k_pvred(
    const bf16_t* __restrict__ p_in, const bf16_t* __restrict__ p_tgt,
    bf16_t* __restrict__ upF) {
  const int b = blockIdx.x;
  const int side = b >> 6, s = b & 63;
  const int d = threadIdx.x;
  const bf16_t* P = (side ? p_tgt : p_in) + s*256 + d;
  float sum = 0.f;
  #pragma unroll 8
  for (int cc = 0; cc < 128; ++cc) sum += (float)P[(size_t)cc * 16384];
  upF[side*16384 + (((s>>4)*8 + (d>>5))<<9) + ((d>>3)&3)*128 + (s&15)*8 + (d&7)] = (bf16_t)sum;
}

// ---------------------------------------------------------------------------
// K_gates: gi = up @ Wih + bih ; gh = h @ Whh + bhh  (fragment layouts)
// ---------------------------------------------------------------------------
__global__ __launch_bounds__(256) void k_gates(
    const bf16_t* __restrict__ upF, const bf16_t* __restrict__ h_bf,
    const bf16_t* __restrict__ wihF_in, const bf16_t* __restrict__ whhF_in,
    const bf16_t* __restrict__ wihF_tgt, const bf16_t* __restrict__ whhF_tgt,
    const float* __restrict__ bih_in, const float* __restrict__ bhh_in,
    const float* __restrict__ bih_tgt, const float* __restrict__ bhh_tgt,
    float* __restrict__ gi, float* __restrict__ gh) {
  const int nchunk = blockIdx.x, which = blockIdx.y, side = blockIdx.z;
  const bf16_t* Aop = (which ? h_bf : upF) + side*16384;
  const bf16_t* WF = side ? (which ? whhF_tgt : wihF_tgt) : (which ? whhF_in : wihF_in);
  const float* bias = side ? (which ? bhh_tgt : bih_tgt) : (which ? bhh_in : bih_in);
  float* out = (which ? gh : gi) + side*49152;
  const int t = threadIdx.x, l = t & 63, w = t >> 6, l16 = l & 15, l4 = l >> 4;
  const int n0 = nchunk*256 + w*64;
  f32x4 acc[4][4] = {};
  for (int ks = 0; ks < 8; ++ks) {
    bf16x8 a[4], b[4];
    #pragma unroll
    for (int mi = 0; mi < 4; ++mi) a[mi] = ld8(Aop + (((size_t)(mi*8 + ks)) << 9) + l*8);
    #pragma unroll
    for (int ni = 0; ni < 4; ++ni)
      b[ni] = ld8(WF + (((size_t)((nchunk*16 + w*4 + ni)*8 + ks)) << 9) + l*8);
    #pragma unroll
    for (int mi = 0; mi < 4; ++mi)
      #pragma unroll
      for (int ni = 0; ni < 4; ++ni) acc[mi][ni] = mfma16(a[mi], b[ni], acc[mi][ni]);
  }
  #pragma unroll
  for (int mi = 0; mi < 4; ++mi)
    #pragma unroll
    for (int ni = 0; ni < 4; ++ni) {
      const int n = n0 + ni*16 + l16;
      const float bb = bias[n];
      #pragma unroll
      for (int rr = 0; rr < 4; ++rr) {
        const int s = mi*16 + l4*4 + rr;
        out[(size_t)s*768 + n] = acc[mi][ni][rr] + bb;
      }
    }
}

// ---------------------------------------------------------------------------
// K_gru_ln: GRUCell elementwise + LN -> hp_f32 (row-major), hpn (fragment)
// ---------------------------------------------------------------------------
__global__ __launch_bounds__(256) void k_gru_ln(
    const float* __restrict__ gi, const float* __restrict__ gh,
    const float* __restrict__ h_f32,
    const float* __restrict__ ln_mi_g, const float* __restrict__ ln_mi_b,
    const float* __restrict__ ln_mt_g, const float* __restrict__ ln_mt_b,
    float* __restrict__ hp_f32, bf16_t* __restrict__ hpnF) {
  const int s = blockIdx.x, side = blockIdx.y;
  const int d = threadIdx.x;
  const float* GI = gi + side*49152 + s*768;
  const float* GH = gh + side*49152 + s*768;
  const float hv = h_f32[side*16384 + s*256 + d];
  const float rg = 1.f / (1.f + __expf(-(GI[d] + GH[d])));
  const float zg = 1.f / (1.f + __expf(-(GI[256 + d] + GH[256 + d])));
  const float ng = tanhf(GI[512 + d] + rg * GH[512 + d]);
  const float hp = (1.f - zg) * ng + zg * hv;
  float a = hp, b2 = hp * hp;
  #pragma unroll
  for (int msk = 1; msk < 64; msk <<= 1) { a += __shfl_xor(a, msk); b2 += __shfl_xor(b2, msk); }
  __shared__ float reda[4], redb[4];
  const int w = d >> 6, lid = d & 63;
  if (lid == 0) { reda[w] = a; redb[w] = b2; }
  __syncthreads();
  const float S1 = reda[0] + reda[1] + reda[2] + reda[3];
  const float S2 = redb[0] + redb[1] + redb[2] + redb[3];
  const float mean = S1 * (1.f/256.f);
  const float rstd = rsqrtf(S2 * (1.f/256.f) - mean*mean + 1e-5f);
  const float* g = side ? ln_mt_g : ln_mi_g;
  const float* bb = side ? ln_mt_b : ln_mi_b;
  const float nv = (hp - mean) * rstd * g[d] + bb[d];
  hp_f32[side*16384 + s*256 + d] = hp;
  hpnF[side*16384 + (((s>>4)*8 + (d>>5))<<9) + ((d>>3)&3)*128 + (s&15)*8 + (d&7)] = (bf16_t)nv;
}

// ---------------------------------------------------------------------------
// K_mlpq: fused  hidden=relu(hpn@W1+b1) ; h_new=hp+hidden@W2+b2 ;
//         (side0, make_q) q = bf16((LN(h_new)@Wq+bq)/16)
// ---------------------------------------------------------------------------
__global__ __launch_bounds__(256) void k_mlpq(
    const bf16_t* __restrict__ hpnF,
    const bf16_t* __restrict__ w1F_in, const bf16_t* __restrict__ w1F_tgt,
    const float* __restrict__ b1_in, const float* __restrict__ b1_tgt,
    const bf16_t* __restrict__ w2F_in, const bf16_t* __restrict__ w2F_tgt,
    const float* __restrict__ b2_in, const float* __restrict__ b2_tgt,
    const float* __restrict__ hp_f32,
    float* __restrict__ h_f32, bf16_t* __restrict__ h_bf, float* __restrict__ slots_out,
    const float* __restrict__ ln_sg, const float* __restrict__ ln_sb,
    const bf16_t* __restrict__ wqF, const float* __restrict__ bq,
    bf16_t* __restrict__ q_bf, int make_q) {
  const int side = blockIdx.x;
  __shared__ __align__(16) bf16_t hid[64][264];
  const int t = threadIdx.x, l = t & 63, w = t >> 6, l16 = l & 15, l4 = l >> 4;
  const int NH = side ? 256 : 128;
  {  // GEMM1
    const bf16_t* Aop = hpnF + side*16384;
    const bf16_t* WF = side ? w1F_tgt : w1F_in;
    const float* b1 = side ? b1_tgt : b1_in;
    const int ntiles = NH >> 6;
    for (int nt = 0; nt < ntiles; ++nt) {
      const int n0 = w*(NH>>2) + nt*16;
      f32x4 acc[4] = {};
      for (int ks = 0; ks < 8; ++ks) {
        bf16x8 b = ld8(WF + (((size_t)((n0>>4)*8 + ks)) << 9) + l*8);
        #pragma unroll
        for (int mt = 0; mt < 4; ++mt)
          acc[mt] = mfma16(ld8(Aop + (((size_t)(mt*8 + ks)) << 9) + l*8), b, acc[mt]);
      }
      const float bb = b1[n0 + l16];
      #pragma unroll
      for (int mt = 0; mt < 4; ++mt)
        #pragma unroll
        for (int rr = 0; rr < 4; ++rr) {
          const int s = mt*16 + l4*4 + rr;
          hid[s][n0 + l16] = (bf16_t)fmaxf(acc[mt][rr] + bb, 0.f);
        }
    }
  }
  __syncthreads();
  {  // GEMM2
    const bf16_t* WF = side ? w2F_tgt : w2F_in;
    const float* b2 = side ? b2_tgt : b2_in;
    const int ksteps = NH >> 5;
    #pragma unroll
    for (int nt = 0; nt < 4; ++nt) {
      const int n0 = w*64 + nt*16;
      f32x4 acc[4] = {};
      for (int ks = 0; ks < ksteps; ++ks) {
        const int k = ks*32 + l4*8;
        bf16x8 b = ld8(WF + (((size_t)((n0>>4)*ksteps + ks)) << 9) + l*8);
        #pragma unroll
        for (int mt = 0; mt < 4; ++mt)
          acc[mt] = mfma16(ld8(&hid[mt*16 + l16][k]), b, acc[mt]);
      }
      const int n = n0 + l16;
      const float bb = b2[n];
      #pragma unroll
      for (int mt = 0; mt < 4; ++mt)
        #pragma unroll
        for (int rr = 0; rr < 4; ++rr) {
          const int s = mt*16 + l4*4 + rr;
          const int idx = side*16384 + s*256 + n;
          const float val = acc[mt][rr] + bb + hp_f32[idx];
          h_f32[idx] = val;
          slots_out[idx] = val;
          h_bf[side*16384 + (((s>>4)*8 + (n>>5))<<9) + ((n>>3)&3)*128 + (s&15)*8 + (n&7)] = (bf16_t)val;
        }
    }
  }
  if (!make_q || side != 0) return;
  __syncthreads();
  {  // LN(h_new) -> hid
    for (int i = 0; i < 16; ++i) {
      const int s = w*16 + i;
      float4 x = *reinterpret_cast<const float4*>(h_f32 + s*256 + 4*l);
      float a = x.x + x.y + x.z + x.w;
      float b2s = x.x*x.x + x.y*x.y + x.z*x.z + x.w*x.w;
      #pragma unroll
      for (int msk = 1; msk < 64; msk <<= 1) { a += __shfl_xor(a, msk); b2s += __shfl_xor(b2s, msk); }
      const float mean = a * (1.f/256.f);
      const float rstd = rsqrtf(b2s * (1.f/256.f) - mean*mean + 1e-5f);
      float4 g4 = *reinterpret_cast<const float4*>(ln_sg + 4*l);
      float4 bb4 = *reinterpret_cast<const float4*>(ln_sb + 4*l);
      bf16x4 pk;
      pk[0] = (bf16_t)((x.x - mean) * rstd * g4.x + bb4.x);
      pk[1] = (bf16_t)((x.y - mean) * rstd * g4.y + bb4.y);
      pk[2] = (bf16_t)((x.z - mean) * rstd * g4.z + bb4.z);
      pk[3] = (bf16_t)((x.w - mean) * rstd * g4.w + bb4.w);
      *reinterpret_cast<bf16x4*>(&hid[s][4*l]) = pk;
    }
  }
  __syncthreads();
  {  // q GEMM
    #pragma unroll
    for (int nt = 0; nt < 4; ++nt) {
      const int n0 = w*64 + nt*16;
      f32x4 acc[4] = {};
      for (int ks = 0; ks < 8; ++ks) {
        const int k = ks*32 + l4*8;
        bf16x8 b = ld8(wqF + (((size_t)((n0>>4)*8 + ks)) << 9) + l*8);
        #pragma unroll
        for (int mt = 0; mt < 4; ++mt)
          acc[mt] = mfma16(ld8(&hid[mt*16 + l16][k]), b, acc[mt]);
      }
      const int d = n0 + l16;
      const float bb = bq[d];
      #pragma unroll
      for (int mt = 0; mt < 4; ++mt) {
        bf16_t* op = q_bf + (((size_t)(mt*8 + (d>>5))) << 9) + ((d>>3)&3)*128 + (d&7);
        #pragma unroll
        for (int rr = 0; rr < 4; ++rr)
          op[(l4*4 + rr)*8] = (bf16_t)((acc[mt][rr] + bb) * 0.0625f);
      }
    }
  }
}

// ---------------------------------------------------------------------------
extern "C" void kernel_launch(void* const* d_in, const int* in_sizes, int n_in,
                              void* d_out, int out_size, void* d_ws, size_t ws_size,
                              hipStream_t stream) {
  (void)in_sizes; (void)n_in; (void)out_size; (void)ws_size;
  const float* inputs     = (const float*)d_in[0];
  const float* target     = (const float*)d_in[1];
  const float* in_slots   = (const float*)d_in[2];
  const float* tgt_slots  = (const float*)d_in[3];
  const float* ln_in_g    = (const float*)d_in[4];
  const float* ln_in_b    = (const float*)d_in[5];
  const float* ln_tgt_g   = (const float*)d_in[6];
  const float* ln_tgt_b   = (const float*)d_in[7];
  const float* Wk  = (const float*)d_in[8];
  const float* bk  = (const float*)d_in[9];
  const float* Wv  = (const float*)d_in[10];
  const float* bv  = (const float*)d_in[11];
  const float* Wvt = (const float*)d_in[12];
  const float* bvt = (const float*)d_in[13];
  const float* ln_slots_g = (const float*)d_in[14];
  const float* ln_slots_b = (const float*)d_in[15];
  const float* Wq  = (const float*)d_in[16];
  const float* bq  = (const float*)d_in[17];
  const float* gru_in_Wih  = (const float*)d_in[18];
  const float* gru_in_Whh  = (const float*)d_in[19];
  const float* gru_in_bih  = (const float*)d_in[20];
  const float* gru_in_bhh  = (const float*)d_in[21];
  const float* gru_tgt_Wih = (const float*)d_in[22];
  const float* gru_tgt_Whh = (const float*)d_in[23];
  const float* gru_tgt_bih = (const float*)d_in[24];
  const float* gru_tgt_bhh = (const float*)d_in[25];
  const float* ln_mi_g = (const float*)d_in[26];
  const float* ln_mi_b = (const float*)d_in[27];
  const float* mi_W1 = (const float*)d_in[28];
  const float* mi_b1 = (const float*)d_in[29];
  const float* mi_W2 = (const float*)d_in[30];
  const float* mi_b2 = (const float*)d_in[31];
  const float* ln_mt_g = (const float*)d_in[32];
  const float* ln_mt_b = (const float*)d_in[33];
  const float* mt_W1 = (const float*)d_in[34];
  const float* mt_b1 = (const float*)d_in[35];
  const float* mt_W2 = (const float*)d_in[36];
  const float* mt_b2 = (const float*)d_in[37];

  char* ws = (char*)d_ws;
  bf16_t* wt      = (bf16_t*)(ws);
  bf16_t* in_kF   = (bf16_t*)(ws + 2490368ull);
  bf16_t* in_vF   = (bf16_t*)(ws + 36044800ull);
  bf16_t* tgt_vF  = (bf16_t*)(ws + 69599232ull);
  bf16_t* attnF   = (bf16_t*)(ws + 103153664ull);
  bf16_t* q_bf    = (bf16_t*)(ws + 111542272ull);
  bf16_t* h_bf    = (bf16_t*)(ws + 111575040ull);
  bf16_t* upF     = (bf16_t*)(ws + 111640576ull);
  bf16_t* hpnF    = (bf16_t*)(ws + 111673344ull);
  float*  h_f32   = (float*)(ws + 111706112ull);
  float*  hp_f32  = (float*)(ws + 111837184ull);
  float*  gi      = (float*)(ws + 111968256ull);
  float*  gh      = (float*)(ws + 112361472ull);
  bf16_t* p_in    = (bf16_t*)(ws + 112754688ull);
  bf16_t* p_tgt   = (bf16_t*)(ws + 116948992ull);       // end 121,143,296

  bf16_t* wkF = wt;
  bf16_t* wvF = wt + 65536;
  bf16_t* wvtF = wt + 131072;
  bf16_t* wqF = wt + 196608;
  bf16_t* wihF_in  = wt + 262144;
  bf16_t* whhF_in  = wt + 458752;
  bf16_t* wihF_tgt = wt + 655360;
  bf16_t* whhF_tgt = wt + 851968;
  bf16_t* w1F_in  = wt + 1048576;
  bf16_t* w2F_in  = wt + 1081344;
  bf16_t* w1F_tgt = wt + 1114112;
  bf16_t* w2F_tgt = wt + 1179648;

  float* attn_out = (float*)d_out + 32768;

  WtArgs wa = {Wk, Wv, Wvt, Wq, gru_in_Wih, gru_in_Whh, gru_tgt_Wih, gru_tgt_Whh,
               mi_W1, mi_W2, mt_W1, mt_W2};
  k_wtrans<<<dim3(48, 12), 256, 0, stream>>>(wa, wt);
  k_init<<<128, 256, 0, stream>>>(in_slots, tgt_slots, h_f32, h_bf);
  k_phaseA<<<dim3(1024, 2), 256, 0, stream>>>(inputs, target, ln_in_g, ln_in_b,
      ln_tgt_g, ln_tgt_b, wkF, wvF, wvtF, bk, bv, bvt, in_kF, in_vF, tgt_vF);
  k_q<<<1, 256, 0, stream>>>(h_f32, ln_slots_g, ln_slots_b, wqF, bq, q_bf);

  for (int it = 0; it < 3; ++it) {
    k_logits<<<256, 256, 0, stream>>>(q_bf, in_kF, attnF, attn_out, it == 2 ? 1 : 0);
    k_pv<<<dim3(128, 2), 256, 0, stream>>>(attnF, in_vF, tgt_vF, p_in, p_tgt);
    k_pvred<<<128, 256, 0, stream>>>(p_in, p_tgt, upF);
    k_gates<<<dim3(3, 2, 2), 256, 0, stream>>>(upF, h_bf, wihF_in, whhF_in,
        wihF_tgt, whhF_tgt, gru_in_bih, gru_in_bhh, gru_tgt_bih, gru_tgt_bhh, gi, gh);
    k_gru_ln<<<dim3(64, 2), 256, 0, stream>>>(gi, gh, h_f32, ln_mi_g, ln_mi_b,
        ln_mt_g, ln_mt_b, hp_f32, hpnF);
    k_mlpq<<<2, 256, 0, stream>>>(hpnF, w1F_in, w1F_tgt, mi_b1, mt_b1,
        w2F_in, w2F_tgt, mi_b2, mt_b2, hp_f32, h_f32, h_bf, (float*)d_out,
        ln_slots_g, ln_slots_b, wqF, bq, q_bf, it < 2 ? 1 : 0);
  }
}